// Round 9
// baseline (857.313 us; speedup 1.0000x reference)
//
#include <hip/hip_runtime.h>
#include <math.h>

#define HH 16
#define DD 64
#define TS 2048
#define EE 1024
#define BB 4
#define MS 12.0f

typedef __attribute__((ext_vector_type(8))) __bf16 bf16x8;
typedef __attribute__((ext_vector_type(2))) __bf16 bf16x2;
typedef __attribute__((ext_vector_type(8))) _Float16 f16x8;
typedef __attribute__((ext_vector_type(4))) float f32x4;

#if defined(__has_builtin)
#if __has_builtin(__builtin_amdgcn_fdot2_f32_bf16)
#define HAS_DOT2 1
#endif
#if __has_builtin(__builtin_amdgcn_exp2f)
#define EXP2(x) __builtin_amdgcn_exp2f(x)
#endif
#endif
#ifndef EXP2
#define EXP2(x) exp2f(x)
#endif

// p = exp(c*0.125 - MS) via single fma + native exp2 (identical in both passes)
__device__ __forceinline__ float pexp(float c) {
    return EXP2(__builtin_fmaf(c, 0.18033688011112042f, -17.312340490667562f));
}

// LDS-only barrier: sync LDS without draining vmcnt (global loads/stores stay in flight).
#define LBAR() asm volatile("s_waitcnt lgkmcnt(0)\n\ts_barrier" ::: "memory")

__device__ __forceinline__ f32x4 mm3(bf16x8 ah, bf16x8 al, bf16x8 bh, bf16x8 bl, f32x4 c) {
    c = __builtin_amdgcn_mfma_f32_16x16x32_bf16(ah, bh, c, 0, 0, 0);
    c = __builtin_amdgcn_mfma_f32_16x16x32_bf16(ah, bl, c, 0, 0, 0);
    c = __builtin_amdgcn_mfma_f32_16x16x32_bf16(al, bh, c, 0, 0, 0);
    return c;
}

__device__ __forceinline__ void gll16(const void* g, void* l) {
    __builtin_amdgcn_global_load_lds(
        (const __attribute__((address_space(1))) unsigned int*)g,
        (__attribute__((address_space(3))) unsigned int*)l, 16, 0, 0);
}

// pack p -> (bf16 hi<<16 | bf16 lo) via truncation split: hi = trunc16(p) (1 AND),
// lo = bf16(p - hi). hi+lo == p to ~2^-17.
__device__ __forceinline__ unsigned pk2(float p) {
    unsigned pu = __builtin_bit_cast(unsigned, p);
    unsigned hb = pu & 0xffff0000u;
    float l = p - __builtin_bit_cast(float, hb);
    __bf16 lb = (__bf16)l;
    return hb | (unsigned)__builtin_bit_cast(unsigned short, lb);
}
__device__ __forceinline__ float upk_hi(unsigned u) { return __builtin_bit_cast(float, u & 0xffff0000u); }
__device__ __forceinline__ float upk_lo(unsigned u) { return __builtin_bit_cast(float, u << 16); }

__device__ __forceinline__ bf16x8 sel_frag(uint4 a, uint4 b, unsigned s) {
    uint4 r;
    r.x = __builtin_amdgcn_perm(a.y, a.x, s);
    r.y = __builtin_amdgcn_perm(a.w, a.z, s);
    r.z = __builtin_amdgcn_perm(b.y, b.x, s);
    r.w = __builtin_amdgcn_perm(b.w, b.z, s);
    return __builtin_bit_cast(bf16x8, r);
}

__device__ __forceinline__ void split8(const float* __restrict__ src,
    __bf16* __restrict__ hi, __bf16* __restrict__ lo, size_t i)
{
    float4 a = *(const float4*)(src + i);
    float4 b = *(const float4*)(src + i + 4);
    float v[8] = {a.x, a.y, a.z, a.w, b.x, b.y, b.z, b.w};
    bf16x8 h, l;
    #pragma unroll
    for (int j = 0; j < 8; ++j) {
        __bf16 x = (__bf16)v[j];
        h[j] = x;
        l[j] = (__bf16)(v[j] - (float)x);
    }
    *(bf16x8*)(hi + i) = h;
    *(bf16x8*)(lo + i) = l;
}

// ---------------- all fp32->bf16 hi/lo splits in ONE launch ----------------
__global__ __launch_bounds__(256) void splitAll(
    const float* __restrict__ q, const float* __restrict__ k, const float* __restrict__ v,
    const float* __restrict__ wq, const float* __restrict__ wk,
    const float* __restrict__ wv, const float* __restrict__ wo,
    __bf16* __restrict__ xqh, __bf16* __restrict__ xql,
    __bf16* __restrict__ xkh, __bf16* __restrict__ xkl,
    __bf16* __restrict__ xvh, __bf16* __restrict__ xvl,
    __bf16* __restrict__ wqh, __bf16* __restrict__ wql,
    __bf16* __restrict__ wkh, __bf16* __restrict__ wkl,
    __bf16* __restrict__ wvh, __bf16* __restrict__ wvl,
    __bf16* __restrict__ woh, __bf16* __restrict__ wol)
{
    const int id = blockIdx.x;
    const float* src;
    __bf16 *hi, *lo;
    size_t base;
    if (id < 12288) {
        int z = id >> 12, loc = id & 4095;
        src = z == 0 ? q : z == 1 ? k : v;
        hi  = z == 0 ? xqh : z == 1 ? xkh : xvh;
        lo  = z == 0 ? xql : z == 1 ? xkl : xvl;
        base = (size_t)loc * 2048;
    } else {
        int w = (id - 12288) >> 9, loc = (id - 12288) & 511;
        src = w == 0 ? wq : w == 1 ? wk : w == 2 ? wv : wo;
        hi  = w == 0 ? wqh : w == 1 ? wkh : w == 2 ? wvh : woh;
        lo  = w == 0 ? wql : w == 1 ? wkl : w == 2 ? wvl : wol;
        base = (size_t)loc * 2048;
    }
    split8(src, hi, lo, base + threadIdx.x * 8);
}

// ---------------- batched QKV projection GEMM (z selects tensor) ----------------
// Outputs written in FRAGMENT-TILED layout per (b,h) head (see attnF).
__global__ __launch_bounds__(256) void gemmQKV(
    const __bf16* __restrict__ xqh, const __bf16* __restrict__ xql,
    const __bf16* __restrict__ xkh, const __bf16* __restrict__ xkl,
    const __bf16* __restrict__ xvh, const __bf16* __restrict__ xvl,
    const __bf16* __restrict__ wqh, const __bf16* __restrict__ wql,
    const __bf16* __restrict__ wkh, const __bf16* __restrict__ wkl,
    const __bf16* __restrict__ wvh, const __bf16* __restrict__ wvl,
    __bf16* __restrict__ Qh, __bf16* __restrict__ Ql,
    __bf16* __restrict__ Kh, __bf16* __restrict__ Kl,
    __bf16* __restrict__ Vh, __bf16* __restrict__ Vl)
{
    const int z = blockIdx.z;
    const __bf16* Ah = z == 0 ? xqh : z == 1 ? xkh : xvh;
    const __bf16* Al = z == 0 ? xql : z == 1 ? xkl : xvl;
    const __bf16* Bh = z == 0 ? wqh : z == 1 ? wkh : wvh;
    const __bf16* Bl = z == 0 ? wql : z == 1 ? wkl : wvl;
    __bf16* Ch = z == 0 ? Qh : z == 1 ? Kh : Vh;
    __bf16* Cl = z == 0 ? Ql : z == 1 ? Kl : Vl;
    const int K = EE;

    __shared__ __bf16 sA[2][128 * 32];
    __shared__ __bf16 sB[2][128 * 32];
    const int tid = threadIdx.x, wave = tid >> 6, lane = tid & 63;
    const int quad = lane >> 4, l15 = lane & 15;
    const int m0 = blockIdx.y * 128, n0 = blockIdx.x * 128;
    const int wm = (wave >> 1) * 64, wn = (wave & 1) * 64;
    const int srow = lane >> 2, scol = (lane & 3) * 8;

    f32x4 acc[4][4];
    #pragma unroll
    for (int i = 0; i < 4; ++i)
        #pragma unroll
        for (int j = 0; j < 4; ++j)
            acc[i][j] = (f32x4){0.f, 0.f, 0.f, 0.f};

    for (int k0 = 0; k0 < K; k0 += 32) {
        __syncthreads();
        #pragma unroll
        for (int i = 0; i < 2; ++i) {
            int c = wave * 2 + i;
            size_t ga = (size_t)(m0 + c * 16 + srow) * K + k0 + scol;
            size_t gb = (size_t)(n0 + c * 16 + srow) * K + k0 + scol;
            gll16(Ah + ga, &sA[0][c * 512]);
            gll16(Al + ga, &sA[1][c * 512]);
            gll16(Bh + gb, &sB[0][c * 512]);
            gll16(Bl + gb, &sB[1][c * 512]);
        }
        __syncthreads();
        bf16x8 fAh[4], fAl[4], fBh[4], fBl[4];
        #pragma unroll
        for (int mb = 0; mb < 4; ++mb) {
            int r = (wm + mb * 16 + l15) * 32 + quad * 8;
            fAh[mb] = *(const bf16x8*)&sA[0][r];
            fAl[mb] = *(const bf16x8*)&sA[1][r];
        }
        #pragma unroll
        for (int nb = 0; nb < 4; ++nb) {
            int r = (wn + nb * 16 + l15) * 32 + quad * 8;
            fBh[nb] = *(const bf16x8*)&sB[0][r];
            fBl[nb] = *(const bf16x8*)&sB[1][r];
        }
        #pragma unroll
        for (int mb = 0; mb < 4; ++mb)
            #pragma unroll
            for (int nb = 0; nb < 4; ++nb)
                acc[mb][nb] = mm3(fAh[mb], fAl[mb], fBh[nb], fBl[nb], acc[mb][nb]);
    }

    #pragma unroll
    for (int mb = 0; mb < 4; ++mb)
        #pragma unroll
        for (int nb = 0; nb < 4; ++nb)
            #pragma unroll
            for (int r = 0; r < 4; ++r) {
                int m = m0 + wm + mb * 16 + quad * 4 + r;
                int n = n0 + wn + nb * 16 + l15;
                float v = acc[mb][nb][r];
                int b = m >> 11, t = m & (TS - 1);
                int h = n >> 6,  d = n & (DD - 1);
                __bf16 hi = (__bf16)v;
                __bf16 lo = (__bf16)(v - (float)hi);
                size_t hbase = ((size_t)b * HH + h) * TS * DD;
                size_t off;
                if (z == 2)
                    off = hbase + (size_t)(((d >> 4) * 64 + (t >> 5)) * 512
                          + (((t >> 3) & 3) * 16 + (d & 15)) * 8 + (t & 7));
                else
                    off = hbase + (size_t)(((t >> 4) * 2 + (d >> 5)) * 512
                          + (((d >> 3) & 3) * 16 + (t & 15)) * 8 + (d & 7));
                Ch[off] = hi;
                Cl[off] = lo;
            }
}

// ---------------- two-pass MFMA flash attention, fragment-tiled Q/K/V ----------
// All Q/K/V fragment loads are contiguous 1KB wave-loads (tile*512 + lane*8).
// s_setprio(1) around MFMA clusters: waves interleave MFMA bursts with VALU
// softmax phases -> scheduler prefers the MFMA-entering wave (attn-shaped win).
// NOTE: plain __launch_bounds__(256) — do NOT add a min-waves clamp (round-3 spill).
__global__ __launch_bounds__(256) void attnF(
    const __bf16* __restrict__ Qh, const __bf16* __restrict__ Ql,
    const __bf16* __restrict__ Kh, const __bf16* __restrict__ Kl,
    const __bf16* __restrict__ VhT, const __bf16* __restrict__ VlT,
    __bf16* __restrict__ avh, __bf16* __restrict__ avl,
    float* __restrict__ out1, _Float16* __restrict__ pp)
{
    __shared__ unsigned Pt[4][32][68];
    const int tid = threadIdx.x, wave = tid >> 6, lane = tid & 63;
    const int quad = lane >> 4, l15 = lane & 15;
    const int linear = blockIdx.x + 64 * blockIdx.y + 256 * blockIdx.z;
    const int bg = (linear & 7) + 8 * (linear >> 9);
    const int tt = (linear >> 3) & 63;
    const int b = bg & 3, g = bg >> 2;
    const int t0 = tt * 32;
    const int h = g * 4 + wave;
    const size_t hoff = (size_t)(b * HH + h);
    const __bf16* qhp = Qh + hoff * TS * DD;
    const __bf16* qlp = Ql + hoff * TS * DD;
    const __bf16* khp = Kh + hoff * TS * DD;
    const __bf16* klp = Kl + hoff * TS * DD;
    const __bf16* vhp = VhT + hoff * DD * TS;
    const __bf16* vlp = VlT + hoff * DD * TS;
    _Float16* myp = pp + (size_t)(g - 1) * ((size_t)BB * TS * TS);

    const int loff = (quad * 16 + l15) * 8;   // lane offset within a 512-elem tile

    bf16x8 fqh[2][2], fql[2][2];
    #pragma unroll
    for (int tb = 0; tb < 2; ++tb)
        #pragma unroll
        for (int ks = 0; ks < 2; ++ks) {
            size_t o = (size_t)((((t0 >> 4) + tb) * 2 + ks) * 512 + loff);
            fqh[tb][ks] = *(const bf16x8*)(qhp + o);
            fql[tb][ks] = *(const bf16x8*)(qlp + o);
        }

    // ---- pass A: l = sum exp(s - MS); no barriers, no LDS ----
    float lacc[2][4];
    #pragma unroll
    for (int tb = 0; tb < 2; ++tb)
        #pragma unroll
        for (int r = 0; r < 4; ++r) lacc[tb][r] = 0.f;

    for (int st = 0; st < 32; ++st) {
        bf16x8 kh[4][2], kl[4][2];
        #pragma unroll
        for (int sb = 0; sb < 4; ++sb) {
            const int kt = ((st * 4 + sb) * 2) * 512 + loff;
            kh[sb][0] = *(const bf16x8*)(khp + kt);
            kh[sb][1] = *(const bf16x8*)(khp + kt + 512);
            kl[sb][0] = *(const bf16x8*)(klp + kt);
            kl[sb][1] = *(const bf16x8*)(klp + kt + 512);
        }
        #pragma unroll
        for (int sb = 0; sb < 4; ++sb)
            #pragma unroll
            for (int tb = 0; tb < 2; ++tb) {
                f32x4 c = (f32x4){0.f, 0.f, 0.f, 0.f};
                __builtin_amdgcn_s_setprio(1);
                c = mm3(fqh[tb][0], fql[tb][0], kh[sb][0], kl[sb][0], c);
                c = mm3(fqh[tb][1], fql[tb][1], kh[sb][1], kl[sb][1], c);
                __builtin_amdgcn_s_setprio(0);
                #pragma unroll
                for (int r = 0; r < 4; ++r)
                    lacc[tb][r] += pexp(c[r]);
            }
    }
    float rf[2][4];
    #pragma unroll
    for (int tb = 0; tb < 2; ++tb)
        #pragma unroll
        for (int r = 0; r < 4; ++r) {
            float v = lacc[tb][r];
            v += __shfl_xor(v, 1);
            v += __shfl_xor(v, 2);
            v += __shfl_xor(v, 4);
            v += __shfl_xor(v, 8);
            rf[tb][r] = 1.0f / v;
        }

    // ---- pass B: exact probs (identical score recompute), PV, out1 ----
    f32x4 oacc[2][4];
    #pragma unroll
    for (int tb = 0; tb < 2; ++tb)
        #pragma unroll
        for (int db = 0; db < 4; ++db) oacc[tb][db] = (f32x4){0.f, 0.f, 0.f, 0.f};

    for (int st = 0; st < 32; ++st) {
        bf16x8 kh[4][2], kl[4][2];
        #pragma unroll
        for (int sb = 0; sb < 4; ++sb) {
            const int kt = ((st * 4 + sb) * 2) * 512 + loff;
            kh[sb][0] = *(const bf16x8*)(khp + kt);
            kh[sb][1] = *(const bf16x8*)(khp + kt + 512);
            kl[sb][0] = *(const bf16x8*)(klp + kt);
            kl[sb][1] = *(const bf16x8*)(klp + kt + 512);
        }
        #pragma unroll
        for (int sb = 0; sb < 4; ++sb)
            #pragma unroll
            for (int tb = 0; tb < 2; ++tb) {
                f32x4 c = (f32x4){0.f, 0.f, 0.f, 0.f};
                __builtin_amdgcn_s_setprio(1);
                c = mm3(fqh[tb][0], fql[tb][0], kh[sb][0], kl[sb][0], c);
                c = mm3(fqh[tb][1], fql[tb][1], kh[sb][1], kl[sb][1], c);
                __builtin_amdgcn_s_setprio(0);
                #pragma unroll
                for (int r = 0; r < 4; ++r) {
                    float p = pexp(c[r]) * rf[tb][r];
                    Pt[wave][tb * 16 + quad * 4 + r][sb * 16 + l15] = pk2(p);
                }
            }
        LBAR();

        // V fragments (tiled) — contiguous 1KB wave-loads
        bf16x8 vh[4][2], vl[4][2];
        #pragma unroll
        for (int db = 0; db < 4; ++db) {
            const int vt = (db * 64 + st * 2) * 512 + loff;
            vh[db][0] = *(const bf16x8*)(vhp + vt);
            vh[db][1] = *(const bf16x8*)(vhp + vt + 512);
            vl[db][0] = *(const bf16x8*)(vlp + vt);
            vl[db][1] = *(const bf16x8*)(vlp + vt + 512);
        }

        bf16x8 fph[2][2], fpl[2][2];
        #pragma unroll
        for (int tb = 0; tb < 2; ++tb)
            #pragma unroll
            for (int ks = 0; ks < 2; ++ks) {
                const unsigned* ppt = &Pt[wave][tb * 16 + l15][ks * 32 + quad * 8];
                uint4 a = *(const uint4*)ppt;
                uint4 bq = *(const uint4*)(ppt + 4);
                fph[tb][ks] = sel_frag(a, bq, 0x07060302u);
                fpl[tb][ks] = sel_frag(a, bq, 0x05040100u);
            }

        // out1 partial: cross-wave (4-head) sum. 1/16 head-average folded into
        // the dot2 weight (2^-4 exact in bf16) — no separate scale muls.
        {
            int row = tid >> 3, s8 = (tid & 7) * 8;
            float vs[8] = {0.f, 0.f, 0.f, 0.f, 0.f, 0.f, 0.f, 0.f};
#ifdef HAS_DOT2
            const bf16x2 w2 = {(__bf16)0.0625f, (__bf16)0.0625f};
#endif
            #pragma unroll
            for (int w = 0; w < 4; ++w) {
                const unsigned* pw = &Pt[w][row][s8];
                uint4 a = *(const uint4*)pw;
                uint4 bq = *(const uint4*)(pw + 4);
                unsigned uu[8] = {a.x, a.y, a.z, a.w, bq.x, bq.y, bq.z, bq.w};
                #pragma unroll
                for (int j = 0; j < 8; ++j) {
#ifdef HAS_DOT2
                    vs[j] = __builtin_amdgcn_fdot2_f32_bf16(
                        __builtin_bit_cast(bf16x2, uu[j]), w2, vs[j], false);
#else
                    vs[j] += (upk_hi(uu[j]) + upk_lo(uu[j])) * 0.0625f;
#endif
                }
            }
            size_t off = ((size_t)b * TS + t0 + row) * TS + st * 64 + s8;
            if (g == 0) {
                float4 o0, o1v;
                o0.x = vs[0]; o0.y = vs[1]; o0.z = vs[2]; o0.w = vs[3];
                o1v.x = vs[4]; o1v.y = vs[5]; o1v.z = vs[6]; o1v.w = vs[7];
                *(float4*)(out1 + off) = o0;
                *(float4*)(out1 + off + 4) = o1v;
            } else {
                f16x8 hv;
                #pragma unroll
                for (int j = 0; j < 8; ++j)
                    hv[j] = (_Float16)vs[j];
                *(f16x8*)(myp + off) = hv;
            }
        }

        __builtin_amdgcn_s_setprio(1);
        #pragma unroll
        for (int db = 0; db < 4; ++db)
            #pragma unroll
            for (int tb = 0; tb < 2; ++tb) {
                f32x4 o = oacc[tb][db];
                o = mm3(fph[tb][0], fpl[tb][0], vh[db][0], vl[db][0], o);
                o = mm3(fph[tb][1], fpl[tb][1], vh[db][1], vl[db][1], o);
                oacc[tb][db] = o;
            }
        __builtin_amdgcn_s_setprio(0);
        LBAR();
    }

    // epilogue: avec as hi/lo bf16 [B*T, H*D]
    #pragma unroll
    for (int tb = 0; tb < 2; ++tb)
        #pragma unroll
        for (int db = 0; db < 4; ++db)
            #pragma unroll
            for (int r = 0; r < 4; ++r) {
                int row = t0 + tb * 16 + quad * 4 + r;
                int col = h * 64 + db * 16 + l15;
                float v = oacc[tb][db][r];
                __bf16 hi = (__bf16)v;
                size_t o = ((size_t)b * TS + row) * EE + col;
                avh[o] = hi;
                avl[o] = (__bf16)(v - (float)hi);
            }
}

// ---------------- output GEMM fused with out1 reduce ----------------
__global__ __launch_bounds__(256) void gemmO(
    const __bf16* __restrict__ Ah, const __bf16* __restrict__ Al,
    const __bf16* __restrict__ Bh, const __bf16* __restrict__ Bl,
    float* __restrict__ Cf, float* __restrict__ out1,
    const _Float16* __restrict__ pp, int M, int N, int K)
{
    __shared__ __bf16 sA[2][128 * 32];
    __shared__ __bf16 sB[2][128 * 32];
    const int tid = threadIdx.x;

    if (blockIdx.x >= 8) {
        // ---- redk path ----
        const size_t P = (size_t)BB * TS * TS;
        size_t r = (size_t)(blockIdx.x - 8) + 128 * blockIdx.y;
        size_t i = (r * 256 + tid) * 8;
        float4 a = *(const float4*)(out1 + i);
        float4 c = *(const float4*)(out1 + i + 4);
        f16x8 q1 = *(const f16x8*)(pp + i);
        f16x8 q2 = *(const f16x8*)(pp + P + i);
        f16x8 q3 = *(const f16x8*)(pp + 2 * P + i);
        a.x += (float)q1[0] + (float)q2[0] + (float)q3[0];
        a.y += (float)q1[1] + (float)q2[1] + (float)q3[1];
        a.z += (float)q1[2] + (float)q2[2] + (float)q3[2];
        a.w += (float)q1[3] + (float)q2[3] + (float)q3[3];
        c.x += (float)q1[4] + (float)q2[4] + (float)q3[4];
        c.y += (float)q1[5] + (float)q2[5] + (float)q3[5];
        c.z += (float)q1[6] + (float)q2[6] + (float)q3[6];
        c.w += (float)q1[7] + (float)q2[7] + (float)q3[7];
        *(float4*)(out1 + i) = a;
        *(float4*)(out1 + i + 4) = c;
        return;
    }

    // ---- GEMM path ----
    const int wave = tid >> 6, lane = tid & 63;
    const int quad = lane >> 4, l15 = lane & 15;
    const int m0 = blockIdx.y * 128, n0 = blockIdx.x * 128;
    const int wm = (wave >> 1) * 64, wn = (wave & 1) * 64;
    const int srow = lane >> 2, scol = (lane & 3) * 8;

    f32x4 acc[4][4];
    #pragma unroll
    for (int i = 0; i < 4; ++i)
        #pragma unroll
        for (int j = 0; j < 4; ++j)
            acc[i][j] = (f32x4){0.f, 0.f, 0.f, 0.f};

    for (int k0 = 0; k0 < K; k0 += 32) {
        __syncthreads();
        #pragma unroll
        for (int i = 0; i < 2; ++i) {
            int c = wave * 2 + i;
            size_t ga = (size_t)(m0 + c * 16 + srow) * K + k0 + scol;
            size_t gb = (size_t)(n0 + c * 16 + srow) * K + k0 + scol;
            gll16(Ah + ga, &sA[0][c * 512]);
            gll16(Al + ga, &sA[1][c * 512]);
            gll16(Bh + gb, &sB[0][c * 512]);
            gll16(Bl + gb, &sB[1][c * 512]);
        }
        __syncthreads();
        bf16x8 fAh[4], fAl[4], fBh[4], fBl[4];
        #pragma unroll
        for (int mb = 0; mb < 4; ++mb) {
            int r = (wm + mb * 16 + l15) * 32 + quad * 8;
            fAh[mb] = *(const bf16x8*)&sA[0][r];
            fAl[mb] = *(const bf16x8*)&sA[1][r];
        }
        #pragma unroll
        for (int nb = 0; nb < 4; ++nb) {
            int r = (wn + nb * 16 + l15) * 32 + quad * 8;
            fBh[nb] = *(const bf16x8*)&sB[0][r];
            fBl[nb] = *(const bf16x8*)&sB[1][r];
        }
        #pragma unroll
        for (int mb = 0; mb < 4; ++mb)
            #pragma unroll
            for (int nb = 0; nb < 4; ++nb)
                acc[mb][nb] = mm3(fAh[mb], fAl[mb], fBh[nb], fBl[nb], acc[mb][nb]);
    }

    #pragma unroll
    for (int mb = 0; mb < 4; ++mb)
        #pragma unroll
        for (int nb = 0; nb < 4; ++nb)
            #pragma unroll
            for (int r = 0; r < 4; ++r) {
                int m = m0 + wm + mb * 16 + quad * 4 + r;
                int n = n0 + wn + nb * 16 + l15;
                Cf[(size_t)m * N + n] = acc[mb][nb][r];
            }
}

extern "C" void kernel_launch(void* const* d_in, const int* in_sizes, int n_in,
                              void* d_out, int out_size, void* d_ws, size_t ws_size,
                              hipStream_t stream)
{
    const float* query = (const float*)d_in[0];
    const float* key_  = (const float*)d_in[1];
    const float* value = (const float*)d_in[2];
    const float* Wq    = (const float*)d_in[3];
    const float* Wk    = (const float*)d_in[4];
    const float* Wv    = (const float*)d_in[5];
    const float* Wo    = (const float*)d_in[6];

    float* out0 = (float*)d_out;                 // [B,T,E]
    float* out1 = out0 + (size_t)BB * TS * EE;   // [B,T,S]

    char* base = (char*)d_ws;
    const size_t U = 16777216;
    __bf16* xqh = (__bf16*)(base + 0 * U);
    __bf16* xql = (__bf16*)(base + 1 * U);
    __bf16* xkh = (__bf16*)(base + 2 * U);
    __bf16* xkl = (__bf16*)(base + 3 * U);
    __bf16* xvh = (__bf16*)(base + 4 * U);
    __bf16* xvl = (__bf16*)(base + 5 * U);
    __bf16* Qhp = (__bf16*)(base + 6 * U);
    __bf16* Qlp = (__bf16*)(base + 7 * U);
    __bf16* Khp = (__bf16*)(base + 8 * U);
    __bf16* Klp = (__bf16*)(base + 9 * U);
    __bf16* VhT = (__bf16*)(base + 10 * U);
    __bf16* VlT = (__bf16*)(base + 11 * U);
    __bf16* avh = (__bf16*)(base + 12 * U);
    __bf16* avl = (__bf16*)(base + 13 * U);
    __bf16* wqh = (__bf16*)(base + 14 * U);
    __bf16* wql = wqh + 1048576;
    __bf16* wkh = wql + 1048576;
    __bf16* wkl = wkh + 1048576;
    __bf16* wvh = wkl + 1048576;
    __bf16* wvl = wvh + 1048576;
    __bf16* woh = wvl + 1048576;
    __bf16* wol = woh + 1048576;
    // fp16 out1 partials for g=1..3 alias the xq/xk/xv splits (dead after gemmQKV)
    _Float16* pp = (_Float16*)(base + 0 * U);

    splitAll<<<14336, 256, 0, stream>>>(query, key_, value, Wq, Wk, Wv, Wo,
                                        xqh, xql, xkh, xkl, xvh, xvl,
                                        wqh, wql, wkh, wkl, wvh, wvl, woh, wol);

    gemmQKV<<<dim3(8, 64, 3), 256, 0, stream>>>(xqh, xql, xkh, xkl, xvh, xvl,
                                                wqh, wql, wkh, wkl, wvh, wvl,
                                                Qhp, Qlp, Khp, Klp, VhT, VlT);

    attnF<<<dim3(64, 4, 4), 256, 0, stream>>>(Qhp, Qlp, Khp, Klp, VhT, VlT,
                                              avh, avl, out1, pp);

    gemmO<<<dim3(136, 64), 256, 0, stream>>>(avh, avl, woh, wol, out0, out1, pp,
                                             8192, 1024, 1024);
}

// Round 10
// 849.904 us; speedup vs baseline: 1.0087x; 1.0087x over previous
//
#include <hip/hip_runtime.h>
#include <math.h>

#define HH 16
#define DD 64
#define TS 2048
#define EE 1024
#define BB 4
#define MS 12.0f

typedef __attribute__((ext_vector_type(8))) __bf16 bf16x8;
typedef __attribute__((ext_vector_type(2))) __bf16 bf16x2;
typedef __attribute__((ext_vector_type(8))) _Float16 f16x8;
typedef __attribute__((ext_vector_type(4))) float f32x4;

#if defined(__has_builtin)
#if __has_builtin(__builtin_amdgcn_fdot2_f32_bf16)
#define HAS_DOT2 1
#endif
#if __has_builtin(__builtin_amdgcn_exp2f)
#define EXP2(x) __builtin_amdgcn_exp2f(x)
#endif
#endif
#ifndef EXP2
#define EXP2(x) exp2f(x)
#endif

// p = exp(c*0.125 - MS) via single fma + native exp2 (identical in all passes)
__device__ __forceinline__ float pexp(float c) {
    return EXP2(__builtin_fmaf(c, 0.18033688011112042f, -17.312340490667562f));
}

// LDS-only barrier: sync LDS without draining vmcnt.
#define LBAR() asm volatile("s_waitcnt lgkmcnt(0)\n\ts_barrier" ::: "memory")

__device__ __forceinline__ f32x4 mm3(bf16x8 ah, bf16x8 al, bf16x8 bh, bf16x8 bl, f32x4 c) {
    c = __builtin_amdgcn_mfma_f32_16x16x32_bf16(ah, bh, c, 0, 0, 0);
    c = __builtin_amdgcn_mfma_f32_16x16x32_bf16(ah, bl, c, 0, 0, 0);
    c = __builtin_amdgcn_mfma_f32_16x16x32_bf16(al, bh, c, 0, 0, 0);
    return c;
}

__device__ __forceinline__ void gll16(const void* g, void* l) {
    __builtin_amdgcn_global_load_lds(
        (const __attribute__((address_space(1))) unsigned int*)g,
        (__attribute__((address_space(3))) unsigned int*)l, 16, 0, 0);
}

// pack p -> (bf16 hi<<16 | bf16 lo) via truncation split.
__device__ __forceinline__ unsigned pk2(float p) {
    unsigned pu = __builtin_bit_cast(unsigned, p);
    unsigned hb = pu & 0xffff0000u;
    float l = p - __builtin_bit_cast(float, hb);
    __bf16 lb = (__bf16)l;
    return hb | (unsigned)__builtin_bit_cast(unsigned short, lb);
}
__device__ __forceinline__ float upk_hi(unsigned u) { return __builtin_bit_cast(float, u & 0xffff0000u); }
__device__ __forceinline__ float upk_lo(unsigned u) { return __builtin_bit_cast(float, u << 16); }

__device__ __forceinline__ bf16x8 sel_frag(uint4 a, uint4 b, unsigned s) {
    uint4 r;
    r.x = __builtin_amdgcn_perm(a.y, a.x, s);
    r.y = __builtin_amdgcn_perm(a.w, a.z, s);
    r.z = __builtin_amdgcn_perm(b.y, b.x, s);
    r.w = __builtin_amdgcn_perm(b.w, b.z, s);
    return __builtin_bit_cast(bf16x8, r);
}

__device__ __forceinline__ void split8(const float* __restrict__ src,
    __bf16* __restrict__ hi, __bf16* __restrict__ lo, size_t i)
{
    float4 a = *(const float4*)(src + i);
    float4 b = *(const float4*)(src + i + 4);
    float v[8] = {a.x, a.y, a.z, a.w, b.x, b.y, b.z, b.w};
    bf16x8 h, l;
    #pragma unroll
    for (int j = 0; j < 8; ++j) {
        __bf16 x = (__bf16)v[j];
        h[j] = x;
        l[j] = (__bf16)(v[j] - (float)x);
    }
    *(bf16x8*)(hi + i) = h;
    *(bf16x8*)(lo + i) = l;
}

// ---------------- all fp32->bf16 hi/lo splits in ONE launch ----------------
__global__ __launch_bounds__(256) void splitAll(
    const float* __restrict__ q, const float* __restrict__ k, const float* __restrict__ v,
    const float* __restrict__ wq, const float* __restrict__ wk,
    const float* __restrict__ wv, const float* __restrict__ wo,
    __bf16* __restrict__ xqh, __bf16* __restrict__ xql,
    __bf16* __restrict__ xkh, __bf16* __restrict__ xkl,
    __bf16* __restrict__ xvh, __bf16* __restrict__ xvl,
    __bf16* __restrict__ wqh, __bf16* __restrict__ wql,
    __bf16* __restrict__ wkh, __bf16* __restrict__ wkl,
    __bf16* __restrict__ wvh, __bf16* __restrict__ wvl,
    __bf16* __restrict__ woh, __bf16* __restrict__ wol)
{
    const int id = blockIdx.x;
    const float* src;
    __bf16 *hi, *lo;
    size_t base;
    if (id < 12288) {
        int z = id >> 12, loc = id & 4095;
        src = z == 0 ? q : z == 1 ? k : v;
        hi  = z == 0 ? xqh : z == 1 ? xkh : xvh;
        lo  = z == 0 ? xql : z == 1 ? xkl : xvl;
        base = (size_t)loc * 2048;
    } else {
        int w = (id - 12288) >> 9, loc = (id - 12288) & 511;
        src = w == 0 ? wq : w == 1 ? wk : w == 2 ? wv : wo;
        hi  = w == 0 ? wqh : w == 1 ? wkh : w == 2 ? wvh : woh;
        lo  = w == 0 ? wql : w == 1 ? wkl : w == 2 ? wvl : wol;
        base = (size_t)loc * 2048;
    }
    split8(src, hi, lo, base + threadIdx.x * 8);
}

// ---------------- batched Q/K projection GEMM (z selects tensor; launched z=0,1) ----
// Outputs written in FRAGMENT-TILED layout per (b,h) head (see attnB).
__global__ __launch_bounds__(256) void gemmQKV(
    const __bf16* __restrict__ xqh, const __bf16* __restrict__ xql,
    const __bf16* __restrict__ xkh, const __bf16* __restrict__ xkl,
    const __bf16* __restrict__ xvh, const __bf16* __restrict__ xvl,
    const __bf16* __restrict__ wqh, const __bf16* __restrict__ wql,
    const __bf16* __restrict__ wkh, const __bf16* __restrict__ wkl,
    const __bf16* __restrict__ wvh, const __bf16* __restrict__ wvl,
    __bf16* __restrict__ Qh, __bf16* __restrict__ Ql,
    __bf16* __restrict__ Kh, __bf16* __restrict__ Kl,
    __bf16* __restrict__ Vh, __bf16* __restrict__ Vl)
{
    const int z = blockIdx.z;
    const __bf16* Ah = z == 0 ? xqh : z == 1 ? xkh : xvh;
    const __bf16* Al = z == 0 ? xql : z == 1 ? xkl : xvl;
    const __bf16* Bh = z == 0 ? wqh : z == 1 ? wkh : wvh;
    const __bf16* Bl = z == 0 ? wql : z == 1 ? wkl : wvl;
    __bf16* Ch = z == 0 ? Qh : z == 1 ? Kh : Vh;
    __bf16* Cl = z == 0 ? Ql : z == 1 ? Kl : Vl;
    const int K = EE;

    __shared__ __bf16 sA[2][128 * 32];
    __shared__ __bf16 sB[2][128 * 32];
    const int tid = threadIdx.x, wave = tid >> 6, lane = tid & 63;
    const int quad = lane >> 4, l15 = lane & 15;
    const int m0 = blockIdx.y * 128, n0 = blockIdx.x * 128;
    const int wm = (wave >> 1) * 64, wn = (wave & 1) * 64;
    const int srow = lane >> 2, scol = (lane & 3) * 8;

    f32x4 acc[4][4];
    #pragma unroll
    for (int i = 0; i < 4; ++i)
        #pragma unroll
        for (int j = 0; j < 4; ++j)
            acc[i][j] = (f32x4){0.f, 0.f, 0.f, 0.f};

    for (int k0 = 0; k0 < K; k0 += 32) {
        __syncthreads();
        #pragma unroll
        for (int i = 0; i < 2; ++i) {
            int c = wave * 2 + i;
            size_t ga = (size_t)(m0 + c * 16 + srow) * K + k0 + scol;
            size_t gb = (size_t)(n0 + c * 16 + srow) * K + k0 + scol;
            gll16(Ah + ga, &sA[0][c * 512]);
            gll16(Al + ga, &sA[1][c * 512]);
            gll16(Bh + gb, &sB[0][c * 512]);
            gll16(Bl + gb, &sB[1][c * 512]);
        }
        __syncthreads();
        bf16x8 fAh[4], fAl[4], fBh[4], fBl[4];
        #pragma unroll
        for (int mb = 0; mb < 4; ++mb) {
            int r = (wm + mb * 16 + l15) * 32 + quad * 8;
            fAh[mb] = *(const bf16x8*)&sA[0][r];
            fAl[mb] = *(const bf16x8*)&sA[1][r];
        }
        #pragma unroll
        for (int nb = 0; nb < 4; ++nb) {
            int r = (wn + nb * 16 + l15) * 32 + quad * 8;
            fBh[nb] = *(const bf16x8*)&sB[0][r];
            fBl[nb] = *(const bf16x8*)&sB[1][r];
        }
        #pragma unroll
        for (int mb = 0; mb < 4; ++mb)
            #pragma unroll
            for (int nb = 0; nb < 4; ++nb)
                acc[mb][nb] = mm3(fAh[mb], fAl[mb], fBh[nb], fBl[nb], acc[mb][nb]);
    }

    #pragma unroll
    for (int mb = 0; mb < 4; ++mb)
        #pragma unroll
        for (int nb = 0; nb < 4; ++nb)
            #pragma unroll
            for (int r = 0; r < 4; ++r) {
                int m = m0 + wm + mb * 16 + quad * 4 + r;
                int n = n0 + wn + nb * 16 + l15;
                float v = acc[mb][nb][r];
                int b = m >> 11, t = m & (TS - 1);
                int h = n >> 6,  d = n & (DD - 1);
                __bf16 hi = (__bf16)v;
                __bf16 lo = (__bf16)(v - (float)hi);
                size_t hbase = ((size_t)b * HH + h) * TS * DD;
                size_t off;
                if (z == 2)
                    off = hbase + (size_t)(((d >> 4) * 64 + (t >> 5)) * 512
                          + (((t >> 3) & 3) * 16 + (d & 15)) * 8 + (t & 7));
                else
                    off = hbase + (size_t)(((t >> 4) * 2 + (d >> 5)) * 512
                          + (((d >> 3) & 3) * 16 + (t & 15)) * 8 + (d & 7));
                Ch[off] = hi;
                Cl[off] = lo;
            }
}

// ---------------- fused: V-projection GEMM  ∥  attention pass A (rf) ----------------
// 1536 blocks in groups of 24 (24 ≡ 0 mod 8 keeps XCD = bid&7 structure):
//   rem<8:   V-GEMM tile (8 per group, one per XCD)   -> VhT/VlT (tiled layout)
//   rem>=8:  pass A block (16 per group, two per XCD) -> rfg = 1/sum exp(s-MS)
// Pass-A bg assignment keeps each XCD on one 4-head K set at a time (L2-resident).
__global__ __launch_bounds__(256) void gvpa(
    const __bf16* __restrict__ xvh, const __bf16* __restrict__ xvl,
    const __bf16* __restrict__ wvh, const __bf16* __restrict__ wvl,
    __bf16* __restrict__ Vh, __bf16* __restrict__ Vl,
    const __bf16* __restrict__ Qh, const __bf16* __restrict__ Ql,
    const __bf16* __restrict__ Kh, const __bf16* __restrict__ Kl,
    float* __restrict__ rfg)
{
    __shared__ __bf16 sA[2][128 * 32];
    __shared__ __bf16 sB[2][128 * 32];
    const int tid = threadIdx.x, wave = tid >> 6, lane = tid & 63;
    const int quad = lane >> 4, l15 = lane & 15;
    const int bid = blockIdx.x;
    const int group = bid / 24, rem = bid % 24;

    if (rem >= 8) {
        // ---- pass A: streaming QK^T rowsum, no LDS, no barriers ----
        const int x = bid & 7;
        const int rk = group * 2 + ((rem - 8) >> 3);
        const int bg = x + 8 * (rk >> 6);
        const int tt = rk & 63;
        const int b = bg & 3, g = bg >> 2;
        const int t0 = tt * 32;
        const int h = g * 4 + wave;
        const size_t hoff = (size_t)(b * HH + h);
        const __bf16* qhp = Qh + hoff * TS * DD;
        const __bf16* qlp = Ql + hoff * TS * DD;
        const __bf16* khp = Kh + hoff * TS * DD;
        const __bf16* klp = Kl + hoff * TS * DD;
        const int loff = (quad * 16 + l15) * 8;

        bf16x8 fqh[2][2], fql[2][2];
        #pragma unroll
        for (int tb = 0; tb < 2; ++tb)
            #pragma unroll
            for (int ks = 0; ks < 2; ++ks) {
                size_t o = (size_t)((((t0 >> 4) + tb) * 2 + ks) * 512 + loff);
                fqh[tb][ks] = *(const bf16x8*)(qhp + o);
                fql[tb][ks] = *(const bf16x8*)(qlp + o);
            }

        float lacc[2][4];
        #pragma unroll
        for (int tb = 0; tb < 2; ++tb)
            #pragma unroll
            for (int r = 0; r < 4; ++r) lacc[tb][r] = 0.f;

        for (int st = 0; st < 32; ++st) {
            bf16x8 kh[4][2], kl[4][2];
            #pragma unroll
            for (int sb = 0; sb < 4; ++sb) {
                const int kt = ((st * 4 + sb) * 2) * 512 + loff;
                kh[sb][0] = *(const bf16x8*)(khp + kt);
                kh[sb][1] = *(const bf16x8*)(khp + kt + 512);
                kl[sb][0] = *(const bf16x8*)(klp + kt);
                kl[sb][1] = *(const bf16x8*)(klp + kt + 512);
            }
            #pragma unroll
            for (int sb = 0; sb < 4; ++sb)
                #pragma unroll
                for (int tb = 0; tb < 2; ++tb) {
                    f32x4 c = (f32x4){0.f, 0.f, 0.f, 0.f};
                    __builtin_amdgcn_s_setprio(1);
                    c = mm3(fqh[tb][0], fql[tb][0], kh[sb][0], kl[sb][0], c);
                    c = mm3(fqh[tb][1], fql[tb][1], kh[sb][1], kl[sb][1], c);
                    __builtin_amdgcn_s_setprio(0);
                    #pragma unroll
                    for (int r = 0; r < 4; ++r)
                        lacc[tb][r] += pexp(c[r]);
                }
        }
        #pragma unroll
        for (int tb = 0; tb < 2; ++tb) {
            float rf4[4];
            #pragma unroll
            for (int r = 0; r < 4; ++r) {
                float v = lacc[tb][r];
                v += __shfl_xor(v, 1);
                v += __shfl_xor(v, 2);
                v += __shfl_xor(v, 4);
                v += __shfl_xor(v, 8);
                rf4[r] = 1.0f / v;
            }
            if (l15 == 0) {
                float4 o;
                o.x = rf4[0]; o.y = rf4[1]; o.z = rf4[2]; o.w = rf4[3];
                *(float4*)(rfg + hoff * TS + t0 + tb * 16 + quad * 4) = o;
            }
        }
        return;
    }

    // ---- V-projection GEMM tile ----
    const int gid = group * 8 + rem;
    const int m0 = (gid >> 3) * 128, n0 = (gid & 7) * 128;
    const int wm = (wave >> 1) * 64, wn = (wave & 1) * 64;
    const int srow = lane >> 2, scol = (lane & 3) * 8;
    const int K = EE;

    f32x4 acc[4][4];
    #pragma unroll
    for (int i = 0; i < 4; ++i)
        #pragma unroll
        for (int j = 0; j < 4; ++j)
            acc[i][j] = (f32x4){0.f, 0.f, 0.f, 0.f};

    for (int k0 = 0; k0 < K; k0 += 32) {
        __syncthreads();
        #pragma unroll
        for (int i = 0; i < 2; ++i) {
            int c = wave * 2 + i;
            size_t ga = (size_t)(m0 + c * 16 + srow) * K + k0 + scol;
            size_t gb = (size_t)(n0 + c * 16 + srow) * K + k0 + scol;
            gll16(xvh + ga, &sA[0][c * 512]);
            gll16(xvl + ga, &sA[1][c * 512]);
            gll16(wvh + gb, &sB[0][c * 512]);
            gll16(wvl + gb, &sB[1][c * 512]);
        }
        __syncthreads();
        bf16x8 fAh[4], fAl[4], fBh[4], fBl[4];
        #pragma unroll
        for (int mb = 0; mb < 4; ++mb) {
            int r = (wm + mb * 16 + l15) * 32 + quad * 8;
            fAh[mb] = *(const bf16x8*)&sA[0][r];
            fAl[mb] = *(const bf16x8*)&sA[1][r];
        }
        #pragma unroll
        for (int nb = 0; nb < 4; ++nb) {
            int r = (wn + nb * 16 + l15) * 32 + quad * 8;
            fBh[nb] = *(const bf16x8*)&sB[0][r];
            fBl[nb] = *(const bf16x8*)&sB[1][r];
        }
        #pragma unroll
        for (int mb = 0; mb < 4; ++mb)
            #pragma unroll
            for (int nb = 0; nb < 4; ++nb)
                acc[mb][nb] = mm3(fAh[mb], fAl[mb], fBh[nb], fBl[nb], acc[mb][nb]);
    }

    #pragma unroll
    for (int mb = 0; mb < 4; ++mb)
        #pragma unroll
        for (int nb = 0; nb < 4; ++nb)
            #pragma unroll
            for (int r = 0; r < 4; ++r) {
                int m = m0 + wm + mb * 16 + quad * 4 + r;
                int n = n0 + wn + nb * 16 + l15;
                float v = acc[mb][nb][r];
                int b = m >> 11, t = m & (TS - 1);
                int h = n >> 6,  d = n & (DD - 1);
                __bf16 hi = (__bf16)v;
                __bf16 lo = (__bf16)(v - (float)hi);
                size_t hbase = ((size_t)b * HH + h) * TS * DD;
                size_t off = hbase + (size_t)(((d >> 4) * 64 + (t >> 5)) * 512
                             + (((t >> 3) & 3) * 16 + (d & 15)) * 8 + (t & 7));
                Vh[off] = hi;
                Vl[off] = lo;
            }
}

// ---------------- pass B: probs (identical score recompute), PV, out1 ----------
// rf precomputed by gvpa. All Q/K/V fragment loads are contiguous 1KB wave-loads.
// NOTE: plain __launch_bounds__(256) — no min-waves clamp (round-3 spill).
__global__ __launch_bounds__(256) void attnB(
    const __bf16* __restrict__ Qh, const __bf16* __restrict__ Ql,
    const __bf16* __restrict__ Kh, const __bf16* __restrict__ Kl,
    const __bf16* __restrict__ VhT, const __bf16* __restrict__ VlT,
    const float* __restrict__ rfg,
    __bf16* __restrict__ avh, __bf16* __restrict__ avl,
    float* __restrict__ out1, _Float16* __restrict__ pp)
{
    __shared__ unsigned Pt[4][32][68];
    const int tid = threadIdx.x, wave = tid >> 6, lane = tid & 63;
    const int quad = lane >> 4, l15 = lane & 15;
    const int linear = blockIdx.x + 64 * blockIdx.y + 256 * blockIdx.z;
    const int bg = (linear & 7) + 8 * (linear >> 9);
    const int tt = (linear >> 3) & 63;
    const int b = bg & 3, g = bg >> 2;
    const int t0 = tt * 32;
    const int h = g * 4 + wave;
    const size_t hoff = (size_t)(b * HH + h);
    const __bf16* qhp = Qh + hoff * TS * DD;
    const __bf16* qlp = Ql + hoff * TS * DD;
    const __bf16* khp = Kh + hoff * TS * DD;
    const __bf16* klp = Kl + hoff * TS * DD;
    const __bf16* vhp = VhT + hoff * DD * TS;
    const __bf16* vlp = VlT + hoff * DD * TS;
    _Float16* myp = pp + (size_t)(g - 1) * ((size_t)BB * TS * TS);

    const int loff = (quad * 16 + l15) * 8;

    bf16x8 fqh[2][2], fql[2][2];
    #pragma unroll
    for (int tb = 0; tb < 2; ++tb)
        #pragma unroll
        for (int ks = 0; ks < 2; ++ks) {
            size_t o = (size_t)((((t0 >> 4) + tb) * 2 + ks) * 512 + loff);
            fqh[tb][ks] = *(const bf16x8*)(qhp + o);
            fql[tb][ks] = *(const bf16x8*)(qlp + o);
        }

    // softmax reciprocal denominators (from gvpa pass A)
    float rf[2][4];
    #pragma unroll
    for (int tb = 0; tb < 2; ++tb) {
        float4 t4 = *(const float4*)(rfg + hoff * TS + t0 + tb * 16 + quad * 4);
        rf[tb][0] = t4.x; rf[tb][1] = t4.y; rf[tb][2] = t4.z; rf[tb][3] = t4.w;
    }

    f32x4 oacc[2][4];
    #pragma unroll
    for (int tb = 0; tb < 2; ++tb)
        #pragma unroll
        for (int db = 0; db < 4; ++db) oacc[tb][db] = (f32x4){0.f, 0.f, 0.f, 0.f};

    for (int st = 0; st < 32; ++st) {
        bf16x8 kh[4][2], kl[4][2];
        #pragma unroll
        for (int sb = 0; sb < 4; ++sb) {
            const int kt = ((st * 4 + sb) * 2) * 512 + loff;
            kh[sb][0] = *(const bf16x8*)(khp + kt);
            kh[sb][1] = *(const bf16x8*)(khp + kt + 512);
            kl[sb][0] = *(const bf16x8*)(klp + kt);
            kl[sb][1] = *(const bf16x8*)(klp + kt + 512);
        }
        #pragma unroll
        for (int sb = 0; sb < 4; ++sb)
            #pragma unroll
            for (int tb = 0; tb < 2; ++tb) {
                f32x4 c = (f32x4){0.f, 0.f, 0.f, 0.f};
                __builtin_amdgcn_s_setprio(1);
                c = mm3(fqh[tb][0], fql[tb][0], kh[sb][0], kl[sb][0], c);
                c = mm3(fqh[tb][1], fql[tb][1], kh[sb][1], kl[sb][1], c);
                __builtin_amdgcn_s_setprio(0);
                #pragma unroll
                for (int r = 0; r < 4; ++r) {
                    float p = pexp(c[r]) * rf[tb][r];
                    Pt[wave][tb * 16 + quad * 4 + r][sb * 16 + l15] = pk2(p);
                }
            }
        LBAR();

        bf16x8 vh[4][2], vl[4][2];
        #pragma unroll
        for (int db = 0; db < 4; ++db) {
            const int vt = (db * 64 + st * 2) * 512 + loff;
            vh[db][0] = *(const bf16x8*)(vhp + vt);
            vh[db][1] = *(const bf16x8*)(vhp + vt + 512);
            vl[db][0] = *(const bf16x8*)(vlp + vt);
            vl[db][1] = *(const bf16x8*)(vlp + vt + 512);
        }

        bf16x8 fph[2][2], fpl[2][2];
        #pragma unroll
        for (int tb = 0; tb < 2; ++tb)
            #pragma unroll
            for (int ks = 0; ks < 2; ++ks) {
                const unsigned* ppt = &Pt[wave][tb * 16 + l15][ks * 32 + quad * 8];
                uint4 a = *(const uint4*)ppt;
                uint4 bq = *(const uint4*)(ppt + 4);
                fph[tb][ks] = sel_frag(a, bq, 0x07060302u);
                fpl[tb][ks] = sel_frag(a, bq, 0x05040100u);
            }

        // out1 partial: cross-wave (4-head) sum; 1/16 folded into dot2 weight.
        {
            int row = tid >> 3, s8 = (tid & 7) * 8;
            float vs[8] = {0.f, 0.f, 0.f, 0.f, 0.f, 0.f, 0.f, 0.f};
#ifdef HAS_DOT2
            const bf16x2 w2 = {(__bf16)0.0625f, (__bf16)0.0625f};
#endif
            #pragma unroll
            for (int w = 0; w < 4; ++w) {
                const unsigned* pw = &Pt[w][row][s8];
                uint4 a = *(const uint4*)pw;
                uint4 bq = *(const uint4*)(pw + 4);
                unsigned uu[8] = {a.x, a.y, a.z, a.w, bq.x, bq.y, bq.z, bq.w};
                #pragma unroll
                for (int j = 0; j < 8; ++j) {
#ifdef HAS_DOT2
                    vs[j] = __builtin_amdgcn_fdot2_f32_bf16(
                        __builtin_bit_cast(bf16x2, uu[j]), w2, vs[j], false);
#else
                    vs[j] += (upk_hi(uu[j]) + upk_lo(uu[j])) * 0.0625f;
#endif
                }
            }
            size_t off = ((size_t)b * TS + t0 + row) * TS + st * 64 + s8;
            if (g == 0) {
                float4 o0, o1v;
                o0.x = vs[0]; o0.y = vs[1]; o0.z = vs[2]; o0.w = vs[3];
                o1v.x = vs[4]; o1v.y = vs[5]; o1v.z = vs[6]; o1v.w = vs[7];
                *(float4*)(out1 + off) = o0;
                *(float4*)(out1 + off + 4) = o1v;
            } else {
                f16x8 hv;
                #pragma unroll
                for (int j = 0; j < 8; ++j)
                    hv[j] = (_Float16)vs[j];
                *(f16x8*)(myp + off) = hv;
            }
        }

        __builtin_amdgcn_s_setprio(1);
        #pragma unroll
        for (int db = 0; db < 4; ++db)
            #pragma unroll
            for (int tb = 0; tb < 2; ++tb) {
                f32x4 o = oacc[tb][db];
                o = mm3(fph[tb][0], fpl[tb][0], vh[db][0], vl[db][0], o);
                o = mm3(fph[tb][1], fpl[tb][1], vh[db][1], vl[db][1], o);
                oacc[tb][db] = o;
            }
        __builtin_amdgcn_s_setprio(0);
        LBAR();
    }

    // epilogue: avec as hi/lo bf16 [B*T, H*D]
    #pragma unroll
    for (int tb = 0; tb < 2; ++tb)
        #pragma unroll
        for (int db = 0; db < 4; ++db)
            #pragma unroll
            for (int r = 0; r < 4; ++r) {
                int row = t0 + tb * 16 + quad * 4 + r;
                int col = h * 64 + db * 16 + l15;
                float v = oacc[tb][db][r];
                __bf16 hi = (__bf16)v;
                size_t o = ((size_t)b * TS + row) * EE + col;
                avh[o] = hi;
                avl[o] = (__bf16)(v - (float)hi);
            }
}

// ---------------- output GEMM fused with out1 reduce ----------------
__global__ __launch_bounds__(256) void gemmO(
    const __bf16* __restrict__ Ah, const __bf16* __restrict__ Al,
    const __bf16* __restrict__ Bh, const __bf16* __restrict__ Bl,
    float* __restrict__ Cf, float* __restrict__ out1,
    const _Float16* __restrict__ pp, int M, int N, int K)
{
    __shared__ __bf16 sA[2][128 * 32];
    __shared__ __bf16 sB[2][128 * 32];
    const int tid = threadIdx.x;

    if (blockIdx.x >= 8) {
        const size_t P = (size_t)BB * TS * TS;
        size_t r = (size_t)(blockIdx.x - 8) + 128 * blockIdx.y;
        size_t i = (r * 256 + tid) * 8;
        float4 a = *(const float4*)(out1 + i);
        float4 c = *(const float4*)(out1 + i + 4);
        f16x8 q1 = *(const f16x8*)(pp + i);
        f16x8 q2 = *(const f16x8*)(pp + P + i);
        f16x8 q3 = *(const f16x8*)(pp + 2 * P + i);
        a.x += (float)q1[0] + (float)q2[0] + (float)q3[0];
        a.y += (float)q1[1] + (float)q2[1] + (float)q3[1];
        a.z += (float)q1[2] + (float)q2[2] + (float)q3[2];
        a.w += (float)q1[3] + (float)q2[3] + (float)q3[3];
        c.x += (float)q1[4] + (float)q2[4] + (float)q3[4];
        c.y += (float)q1[5] + (float)q2[5] + (float)q3[5];
        c.z += (float)q1[6] + (float)q2[6] + (float)q3[6];
        c.w += (float)q1[7] + (float)q2[7] + (float)q3[7];
        *(float4*)(out1 + i) = a;
        *(float4*)(out1 + i + 4) = c;
        return;
    }

    const int wave = tid >> 6, lane = tid & 63;
    const int quad = lane >> 4, l15 = lane & 15;
    const int m0 = blockIdx.y * 128, n0 = blockIdx.x * 128;
    const int wm = (wave >> 1) * 64, wn = (wave & 1) * 64;
    const int srow = lane >> 2, scol = (lane & 3) * 8;

    f32x4 acc[4][4];
    #pragma unroll
    for (int i = 0; i < 4; ++i)
        #pragma unroll
        for (int j = 0; j < 4; ++j)
            acc[i][j] = (f32x4){0.f, 0.f, 0.f, 0.f};

    for (int k0 = 0; k0 < K; k0 += 32) {
        __syncthreads();
        #pragma unroll
        for (int i = 0; i < 2; ++i) {
            int c = wave * 2 + i;
            size_t ga = (size_t)(m0 + c * 16 + srow) * K + k0 + scol;
            size_t gb = (size_t)(n0 + c * 16 + srow) * K + k0 + scol;
            gll16(Ah + ga, &sA[0][c * 512]);
            gll16(Al + ga, &sA[1][c * 512]);
            gll16(Bh + gb, &sB[0][c * 512]);
            gll16(Bl + gb, &sB[1][c * 512]);
        }
        __syncthreads();
        bf16x8 fAh[4], fAl[4], fBh[4], fBl[4];
        #pragma unroll
        for (int mb = 0; mb < 4; ++mb) {
            int r = (wm + mb * 16 + l15) * 32 + quad * 8;
            fAh[mb] = *(const bf16x8*)&sA[0][r];
            fAl[mb] = *(const bf16x8*)&sA[1][r];
        }
        #pragma unroll
        for (int nb = 0; nb < 4; ++nb) {
            int r = (wn + nb * 16 + l15) * 32 + quad * 8;
            fBh[nb] = *(const bf16x8*)&sB[0][r];
            fBl[nb] = *(const bf16x8*)&sB[1][r];
        }
        #pragma unroll
        for (int mb = 0; mb < 4; ++mb)
            #pragma unroll
            for (int nb = 0; nb < 4; ++nb)
                acc[mb][nb] = mm3(fAh[mb], fAl[mb], fBh[nb], fBl[nb], acc[mb][nb]);
    }

    #pragma unroll
    for (int mb = 0; mb < 4; ++mb)
        #pragma unroll
        for (int nb = 0; nb < 4; ++nb)
            #pragma unroll
            for (int r = 0; r < 4; ++r) {
                int m = m0 + wm + mb * 16 + quad * 4 + r;
                int n = n0 + wn + nb * 16 + l15;
                Cf[(size_t)m * N + n] = acc[mb][nb][r];
            }
}

extern "C" void kernel_launch(void* const* d_in, const int* in_sizes, int n_in,
                              void* d_out, int out_size, void* d_ws, size_t ws_size,
                              hipStream_t stream)
{
    const float* query = (const float*)d_in[0];
    const float* key_  = (const float*)d_in[1];
    const float* value = (const float*)d_in[2];
    const float* Wq    = (const float*)d_in[3];
    const float* Wk    = (const float*)d_in[4];
    const float* Wv    = (const float*)d_in[5];
    const float* Wo    = (const float*)d_in[6];

    float* out0 = (float*)d_out;                 // [B,T,E]
    float* out1 = out0 + (size_t)BB * TS * EE;   // [B,T,S]

    char* base = (char*)d_ws;
    const size_t U = 16777216;
    __bf16* xqh = (__bf16*)(base + 0 * U);
    __bf16* xql = (__bf16*)(base + 1 * U);
    __bf16* xkh = (__bf16*)(base + 2 * U);
    __bf16* xkl = (__bf16*)(base + 3 * U);
    __bf16* xvh = (__bf16*)(base + 4 * U);
    __bf16* xvl = (__bf16*)(base + 5 * U);
    __bf16* Qhp = (__bf16*)(base + 6 * U);
    __bf16* Qlp = (__bf16*)(base + 7 * U);
    __bf16* Khp = (__bf16*)(base + 8 * U);
    __bf16* Klp = (__bf16*)(base + 9 * U);
    __bf16* VhT = (__bf16*)(base + 10 * U);
    __bf16* VlT = (__bf16*)(base + 11 * U);
    __bf16* avh = (__bf16*)(base + 12 * U);
    __bf16* avl = (__bf16*)(base + 13 * U);
    __bf16* wqh = (__bf16*)(base + 14 * U);
    __bf16* wql = wqh + 1048576;
    __bf16* wkh = wql + 1048576;
    __bf16* wkl = wkh + 1048576;
    __bf16* wvh = wkl + 1048576;
    __bf16* wvl = wvh + 1048576;
    __bf16* woh = wvl + 1048576;
    __bf16* wol = woh + 1048576;
    float*  rfg = (float*)(base + 15 * U);       // [B,H,T] fp32 = 512 KB
    // fp16 out1 partials for g=1..3 alias the xq/xk/xv splits (dead after QKV GEMMs)
    _Float16* pp = (_Float16*)(base + 0 * U);

    splitAll<<<14336, 256, 0, stream>>>(query, key_, value, Wq, Wk, Wv, Wo,
                                        xqh, xql, xkh, xkl, xvh, xvl,
                                        wqh, wql, wkh, wkl, wvh, wvl, woh, wol);

    // Q and K projections only
    gemmQKV<<<dim3(8, 64, 2), 256, 0, stream>>>(xqh, xql, xkh, xkl, xvh, xvl,
                                                wqh, wql, wkh, wkl, wvh, wvl,
                                                Qhp, Qlp, Khp, Klp, VhT, VlT);

    // V projection overlapped with attention pass A (rf)
    gvpa<<<1536, 256, 0, stream>>>(xvh, xvl, wvh, wvl, VhT, VlT,
                                   Qhp, Qlp, Khp, Klp, rfg);

    attnB<<<dim3(64, 4, 4), 256, 0, stream>>>(Qhp, Qlp, Khp, Klp, VhT, VlT, rfg,
                                              avh, avl, out1, pp);

    gemmO<<<dim3(136, 64), 256, 0, stream>>>(avh, avl, woh, wol, out0, out1, pp,
                                             8192, 1024, 1024);
}